// Round 10
// baseline (262.484 us; speedup 1.0000x reference)
//
#include <hip/hip_runtime.h>
#include <hip/hip_bf16.h>

// ---------------------------------------------------------------------------
// Attention_CA: out = Proj( Softmax(mask, scale * (q Wq^T) (kv Wkv^T)_K^T) (kv Wkv^T)_V )
// B=4, N=1024, M=2048, C=768, H=12, d=64.
// R10: attn drops V LDS-staging (m169/common-mistake#7: V is L2-resident --
// per-head V^T = 256KB, and XCD swizzle pins all 16 blocks of head bh to XCD
// bh%8, so V is L2-local). PV B-fragments loaded directly from global vt into
// regs at loop-top (~400cyc cover: barrier+QK^T+softmax vs ~200cyc L2 hit).
// Halves attn LDS traffic (was ~74% LDS-pipe busy). K staging unchanged.
// gemm12 = R7 2ph-dbuf gload_lds; gemm3 = R9 64x64/768blk (noise-equivalent).
// Predicted attn 49.8 -> ~43-46, e2e ~207-210.
// ---------------------------------------------------------------------------

typedef short    s16x8  __attribute__((ext_vector_type(8)));
typedef short    s16x4  __attribute__((ext_vector_type(4)));
typedef float    f32x4  __attribute__((ext_vector_type(4)));
typedef _Float16 f16x8  __attribute__((ext_vector_type(8)));
typedef _Float16 f16x4  __attribute__((ext_vector_type(4)));
typedef _Float16 f16x2  __attribute__((ext_vector_type(2)));

#define NUM_H 12
#define DIM   768
#define NQ    1024
#define MK    2048
#define QK_SCALE_LOG2E 0.18033688f

__device__ __forceinline__ short f2h(float v) {
    _Float16 h = (_Float16)v;                 // RNE
    return __builtin_bit_cast(short, h);
}
__device__ __forceinline__ f32x4 mfma16x32(f16x8 a, f16x8 b, f32x4 c) {
    return __builtin_amdgcn_mfma_f32_16x16x32_f16(a, b, c, 0, 0, 0);
}
__device__ __forceinline__ f16x2 pk2h(float a, float b) {   // RTZ (P only)
    return __builtin_bit_cast(f16x2, __builtin_amdgcn_cvt_pkrtz(a, b));
}

// ------------------- prep: all casts + mask byte-pack ----------------------
__global__ __launch_bounds__(256) void prep_kernel(
    const float* __restrict__ q, const float* __restrict__ kv,
    const float* __restrict__ Wq, const float* __restrict__ Wkv,
    const float* __restrict__ Wp, const int* __restrict__ mask,
    short* __restrict__ q_h, short* __restrict__ kv_h,
    short* __restrict__ Wq_h, short* __restrict__ Wkv_h,
    short* __restrict__ Wp_h, unsigned char* __restrict__ mbytes)
{
    int bid = blockIdx.x;
    if (bid < 5760) {
        const float* s; short* d; long base;
        if (bid < 1536)      { s = q;   d = q_h;   base = (long)bid * 2048; }
        else if (bid < 4608) { s = kv;  d = kv_h;  base = (long)(bid - 1536) * 2048; }
        else if (bid < 4896) { s = Wq;  d = Wq_h;  base = (long)(bid - 4608) * 2048; }
        else if (bid < 5472) { s = Wkv; d = Wkv_h; base = (long)(bid - 4896) * 2048; }
        else                 { s = Wp;  d = Wp_h;  base = (long)(bid - 5472) * 2048; }
        long i = base + threadIdx.x * 8;
        float4 a = *(const float4*)(s + i);
        float4 b = *(const float4*)(s + i + 4);
        s16x8 r;
        r[0] = f2h(a.x); r[1] = f2h(a.y); r[2] = f2h(a.z); r[3] = f2h(a.w);
        r[4] = f2h(b.x); r[5] = f2h(b.y); r[6] = f2h(b.z); r[7] = f2h(b.w);
        *(s16x8*)(d + i) = r;
    } else {
        long base = (long)(bid - 5760) * 2048 + threadIdx.x * 8;
        int4 m0 = *(const int4*)(mask + base);
        int4 m1 = *(const int4*)(mask + base + 4);
        unsigned v = (unsigned)(m0.x != 0)        | ((unsigned)(m0.y != 0) << 1)
                   | ((unsigned)(m0.z != 0) << 2) | ((unsigned)(m0.w != 0) << 3)
                   | ((unsigned)(m1.x != 0) << 4) | ((unsigned)(m1.y != 0) << 5)
                   | ((unsigned)(m1.z != 0) << 6) | ((unsigned)(m1.w != 0) << 7);
        mbytes[base >> 3] = (unsigned char)v;
    }
}

// ---------------------------- GEMM core: C = A @ Bt^T ----------------------
// R7 (kept): double-buffered global_load_lds. Each buffer: A[128][64]+
// B[128][64] linear (32KB). Source chunk inverse-XOR-swizzled, fragment reads
// XOR the same key -> conflict-free b128 + wave-linear DMA dest. ONE barrier
// per K-step: stage(next) -> ds_read+MFMA(cur) -> barrier (drain+release).
__device__ __forceinline__ void gemm_core(
    short* smem,
    const short* __restrict__ A, const short* __restrict__ Bt,
    int Ncols, int mode,
    short* __restrict__ outb, short* __restrict__ outb2, int bid)
{
    int ntiles = Ncols >> 7;
    int m0 = (bid / ntiles) << 7;
    int n0 = (bid % ntiles) << 7;
    int t = threadIdx.x;
    int w = t >> 6, lane = t & 63, quad = lane >> 4, l16 = lane & 15;
    int wm = (w & 1) << 6, wn = (w >> 1) << 6;

    f32x4 zero4 = {0.f, 0.f, 0.f, 0.f};
    f32x4 acc[4][4];
    for (int i = 0; i < 4; i++)
        for (int j = 0; j < 4; j++) acc[i][j] = zero4;

    int srow = (w << 3) + (lane >> 3);                  // 0..31 (issue-0 row)
    int scol = (((lane & 7) ^ (lane >> 3)) << 3);       // source col in shorts
    const short* Asrc = A + (long)(m0 + srow) * DIM + scol;
    const short* Bsrc = Bt + (long)(n0 + srow) * DIM + scol;
    int dstoff = (w << 9) + (lane << 3);                // shorts; byte w*1024+lane*16

    auto stage = [&](short* bufA, short* bufB, int kt) {
        #pragma unroll
        for (int i = 0; i < 4; i++) {
            __builtin_amdgcn_global_load_lds(
                (const unsigned int*)(Asrc + (long)i * 32 * DIM + kt),
                (unsigned int*)(bufA + dstoff + i * 2048), 16, 0, 0);
            __builtin_amdgcn_global_load_lds(
                (const unsigned int*)(Bsrc + (long)i * 32 * DIM + kt),
                (unsigned int*)(bufB + dstoff + i * 2048), 16, 0, 0);
        }
    };

    int swl = l16 & 7;           // read-side XOR key (row&7 = l16&7)

    stage(smem, smem + 8192, 0);
    __syncthreads();             // prologue drain (unavoidable)

    for (int kt = 0; kt < DIM; kt += 64) {
        short* Ac = smem + ((kt & 64) ? 16384 : 0);
        short* Bc = Ac + 8192;
        if (kt + 64 < DIM) {
            short* An = smem + ((kt & 64) ? 0 : 16384);
            stage(An, An + 8192, kt + 64);      // issue BEFORE compute
        }
        #pragma unroll
        for (int kh = 0; kh < 2; kh++) {
            f16x8 af[4], bfr[4];
            #pragma unroll
            for (int i = 0; i < 4; i++)
                af[i] = __builtin_bit_cast(f16x8, *(const s16x8*)(
                    Ac + ((wm + i * 16 + l16) << 6)
                       + ((((kh << 2) | quad) ^ swl) << 3)));
            #pragma unroll
            for (int j = 0; j < 4; j++)
                bfr[j] = __builtin_bit_cast(f16x8, *(const s16x8*)(
                    Bc + ((wn + j * 16 + l16) << 6)
                       + ((((kh << 2) | quad) ^ swl) << 3)));
            #pragma unroll
            for (int i = 0; i < 4; i++)
                #pragma unroll
                for (int j = 0; j < 4; j++)
                    acc[i][j] = mfma16x32(af[i], bfr[j], acc[i][j]);
        }
        __syncthreads();         // drain prefetch (under MFMA) + release buffer
    }

    short (*Cs)[136] = (short(*)[136])smem;
    bool vreg = (mode == 1) && (n0 >= DIM);

    if (!vreg) {
        float sc = (mode == 0) ? QK_SCALE_LOG2E : 1.0f;
        #pragma unroll
        for (int i = 0; i < 4; i++)
            #pragma unroll
            for (int j = 0; j < 4; j++)
                #pragma unroll
                for (int r = 0; r < 4; r++)
                    Cs[wm + i * 16 + quad * 4 + r][wn + j * 16 + l16] =
                        f2h(acc[i][j][r] * sc);
    } else {
        #pragma unroll
        for (int i = 0; i < 4; i++)
            #pragma unroll
            for (int j = 0; j < 4; j++) {
                int c = wn + j * 16 + l16;
                int r0 = wm + i * 16 + quad * 4;
                s16x4 pk;
                pk[0] = f2h(acc[i][j][0]); pk[1] = f2h(acc[i][j][1]);
                pk[2] = f2h(acc[i][j][2]); pk[3] = f2h(acc[i][j][3]);
                *(s16x4*)&Cs[c][r0] = pk;            // transposed: Cs[dd][m]
            }
    }
    __syncthreads();

    if (!vreg) {
        int hb2 = n0 >> 6;
        long rowsN = (mode == 0) ? NQ : MK;
        int b = (int)(m0 / rowsN);
        int rb = (int)(m0 % rowsN);
        short* ob0 = outb + ((long)(b * NUM_H + hb2) * rowsN + rb) * 64;
        short* ob1 = outb + ((long)(b * NUM_H + hb2 + 1) * rowsN + rb) * 64;
        #pragma unroll
        for (int k2 = 0; k2 < 8; k2++) {
            int ch = k2 * 256 + t;
            int half = ch >> 10, off = ch & 1023;
            s16x8 vd = *(const s16x8*)&Cs[off >> 3][(half << 6) + ((off & 7) << 3)];
            *(s16x8*)((half ? ob1 : ob0) + off * 8) = vd;
        }
    } else {
        int hb2 = (n0 - DIM) >> 6;
        int b = m0 >> 11, rb = m0 & 2047;
        #pragma unroll
        for (int k2 = 0; k2 < 8; k2++) {
            int ch = k2 * 256 + t;
            int c = ch >> 4, woff = (ch & 15) << 3;
            s16x8 vd = *(const s16x8*)&Cs[c][woff];
            int half = c >> 6, dd = c & 63;
            *(s16x8*)(outb2 + (((long)(b * NUM_H + hb2 + half) * 64 + dd) * MK + rb) + woff) = vd;
        }
    }
}

__global__ __launch_bounds__(256) void gemm12_kernel(
    const short* __restrict__ qh, const short* __restrict__ Wqh,
    const short* __restrict__ kvh, const short* __restrict__ Wkvh,
    short* __restrict__ qp, short* __restrict__ kk, short* __restrict__ vt)
{
    __shared__ short smem[32768];      // 64KB: 2 x (A 16KB + B 16KB)
    if (blockIdx.x < 192)
        gemm_core(smem, qh, Wqh, 768, 0, qp, nullptr, blockIdx.x);
    else
        gemm_core(smem, kvh, Wkvh, 1536, 1, kk, vt, blockIdx.x - 192);
}

// -------------------- gemm3: 64x64 tiles, 768 blocks -----------------------
__global__ __launch_bounds__(256) void gemm3_kernel(
    const short* __restrict__ xb, const short* __restrict__ Wph,
    const float* __restrict__ bias, float* __restrict__ out)
{
    __shared__ short smem[16384];      // 32KB: 2 x (A 8KB + B 8KB)
    int bid = blockIdx.x;
    int m0 = (bid / 12) << 6;
    int n0 = (bid % 12) << 6;
    int t = threadIdx.x;
    int w = t >> 6, lane = t & 63, quad = lane >> 4, l16 = lane & 15;
    int wm = (w & 1) << 5, wn = (w >> 1) << 5;

    f32x4 zero4 = {0.f, 0.f, 0.f, 0.f};
    f32x4 acc[2][2];
    for (int i = 0; i < 2; i++)
        for (int j = 0; j < 2; j++) acc[i][j] = zero4;

    int srow = t >> 3;                                  // 0..31
    int scol = (((t & 7) ^ ((t >> 3) & 7)) << 3);
    const short* Asrc = xb + (long)(m0 + srow) * DIM + scol;
    const short* Bsrc = Wph + (long)(n0 + srow) * DIM + scol;
    int dstoff = t << 3;                                // shorts; t*16 bytes

    auto stage = [&](short* bufA, short* bufB, int kt) {
        #pragma unroll
        for (int i = 0; i < 2; i++) {
            __builtin_amdgcn_global_load_lds(
                (const unsigned int*)(Asrc + (long)i * 32 * DIM + kt),
                (unsigned int*)(bufA + dstoff + i * 2048), 16, 0, 0);
            __builtin_amdgcn_global_load_lds(
                (const unsigned int*)(Bsrc + (long)i * 32 * DIM + kt),
                (unsigned int*)(bufB + dstoff + i * 2048), 16, 0, 0);
        }
    };

    int swl = l16 & 7;

    stage(smem, smem + 4096, 0);
    __syncthreads();

    for (int kt = 0; kt < DIM; kt += 64) {
        short* Ac = smem + ((kt & 64) ? 8192 : 0);
        short* Bc = Ac + 4096;
        if (kt + 64 < DIM) {
            short* An = smem + ((kt & 64) ? 0 : 8192);
            stage(An, An + 4096, kt + 64);
        }
        #pragma unroll
        for (int kh = 0; kh < 2; kh++) {
            f16x8 af[2], bfr[2];
            #pragma unroll
            for (int i = 0; i < 2; i++)
                af[i] = __builtin_bit_cast(f16x8, *(const s16x8*)(
                    Ac + ((wm + i * 16 + l16) << 6)
                       + ((((kh << 2) | quad) ^ swl) << 3)));
            #pragma unroll
            for (int j = 0; j < 2; j++)
                bfr[j] = __builtin_bit_cast(f16x8, *(const s16x8*)(
                    Bc + ((wn + j * 16 + l16) << 6)
                       + ((((kh << 2) | quad) ^ swl) << 3)));
            #pragma unroll
            for (int i = 0; i < 2; i++)
                #pragma unroll
                for (int j = 0; j < 2; j++)
                    acc[i][j] = mfma16x32(af[i], bfr[j], acc[i][j]);
        }
        __syncthreads();
    }

    #pragma unroll
    for (int i = 0; i < 2; i++)
        #pragma unroll
        for (int j = 0; j < 2; j++)
            #pragma unroll
            for (int r = 0; r < 4; r++) {
                int row = m0 + wm + i * 16 + quad * 4 + r;
                int col = n0 + wn + j * 16 + l16;
                out[(long)row * DIM + col] = acc[i][j][r] + bias[col];
            }
}

// -------------- flash attention (R10: V direct from L2) --------------------
// 4 waves x 16 q-rows, KVBLK=64. K staged in LDS (permuted rows + XOR
// swizzle); V fragments loaded DIRECTLY from global vt (L2-resident per
// head; all 16 blocks of head bh sit on XCD bh%8). bvr loads issued at
// loop-top -> covered by barrier + QK^T + softmax.
__global__ __launch_bounds__(256) void attn_kernel(
    const short* __restrict__ qp, const short* __restrict__ kk,
    const short* __restrict__ vt, const unsigned* __restrict__ mb,
    short* __restrict__ xb)
{
    __shared__ short qs[64][72];       // Q tile; reused as O staging
    __shared__ short ks[64][64];       // K tile, rows permuted, XOR-swizzled

    int bid = blockIdx.x;
    int bh = bid % 48;                 // XCD swizzle: head bh -> XCD bh%8
    int nt = bid / 48;
    int h = bh % NUM_H, b = bh / NUM_H;
    int n0 = nt << 6;
    int t = threadIdx.x, w = t >> 6, lane = t & 63, quad = lane >> 4, l16 = lane & 15;

    const short* qbase = qp + ((long)bh * NQ + n0) * 64;
    const short* kbase = kk + (long)bh * MK * 64;
    const short* vbase = vt + (long)bh * 64 * MK;
    const unsigned* mrow = mb + ((long)b * NQ + n0 + (w << 4) + l16) * 64;

    {   // stage Q tile once
        int qr = t >> 2, c0q = (t & 3) << 4;
        *(s16x8*)&qs[qr][c0q]     = *(const s16x8*)(qbase + qr * 64 + c0q);
        *(s16x8*)&qs[qr][c0q + 8] = *(const s16x8*)(qbase + qr * 64 + c0q + 8);
    }
    __syncthreads();
    f16x8 bq[2];                       // B-frag: this wave's 16 q-rows
    #pragma unroll
    for (int kh = 0; kh < 2; kh++)
        bq[kh] = __builtin_bit_cast(f16x8,
            *(const s16x8*)&qs[(w << 4) + l16][kh * 32 + quad * 8]);

    int sr = t >> 2, c0 = (t & 3) << 4;
    int pr = (sr & 32) + ((sr & 4) << 2) + ((sr & 24) >> 1) + (sr & 3);
    int swk = (pr & 7) << 3;           // XOR key for ks writes (physical row pr)
    int swl = (l16 & 7) << 3;          // XOR key for fragment reads (row = *16+l16)
    const short* kp = kbase + (long)sr * 64 + c0;

    // per-lane V fragment base pointers: row jd*16+l16, col quad*8
    const short* vb[4];
    #pragma unroll
    for (int jd = 0; jd < 4; jd++)
        vb[jd] = vbase + (long)(jd * 16 + l16) * MK + quad * 8;

    s16x8 k0 = *(const s16x8*)(kp);
    s16x8 k1 = *(const s16x8*)(kp + 8);
    uint2 mwv = *(const uint2*)(mrow);

    f32x4 zero4 = {0.f, 0.f, 0.f, 0.f};
    f32x4 o[4], ol = zero4;
    for (int j = 0; j < 4; j++) o[j] = zero4;
    const f16x8 ones = {(_Float16)1.f, (_Float16)1.f, (_Float16)1.f, (_Float16)1.f,
                        (_Float16)1.f, (_Float16)1.f, (_Float16)1.f, (_Float16)1.f};

    for (int mt = 0; mt < MK; mt += 64) {
        // V fragments for THIS tile: direct global loads (L2-hot), issued
        // early so barrier + QK^T + softmax cover the latency.
        s16x8 bvr[2][4];
        #pragma unroll
        for (int j2 = 0; j2 < 2; j2++)
            #pragma unroll
            for (int jd = 0; jd < 4; jd++)
                bvr[j2][jd] = *(const s16x8*)(vb[jd] + mt + j2 * 32);

        __syncthreads();
        *(s16x8*)&ks[pr][c0 ^ swk]       = k0;
        *(s16x8*)&ks[pr][(c0 + 8) ^ swk] = k1;
        unsigned cm0 = mwv.x, cm1 = mwv.y;      // save pre-clobber
        __syncthreads();
        if (mt + 64 < MK) {
            k0 = *(const s16x8*)(kp + (long)(mt + 64) * 64);
            k1 = *(const s16x8*)(kp + (long)(mt + 64) * 64 + 8);
            mwv = *(const uint2*)(mrow + ((mt + 64) >> 5));
        }

        // S^T = K Q^T; s[jj=j2*2+sub][rr] = S[qrow=l16][m=j2*32+quad*8+sub*4+rr]
        f32x4 s[4];
        #pragma unroll
        for (int jj = 0; jj < 4; jj++) s[jj] = zero4;
        __builtin_amdgcn_s_setprio(1);
        #pragma unroll
        for (int kh = 0; kh < 2; kh++)
            #pragma unroll
            for (int jj = 0; jj < 4; jj++) {
                f16x8 ak = __builtin_bit_cast(f16x8,
                    *(const s16x8*)&ks[jj * 16 + l16][(kh * 32 + quad * 8) ^ swl]);
                s[jj] = mfma16x32(ak, bq[kh], s[jj]);
            }
        __builtin_amdgcn_s_setprio(0);

        // p = mask ? exp2(s) : 0, packed to K=32 fp16 A-fragments
        f16x8 pa[2];
        #pragma unroll
        for (int j2 = 0; j2 < 2; j2++) {
            unsigned wsel = j2 ? cm1 : cm0;
            f16x2 pk[4];
            #pragma unroll
            for (int sub = 0; sub < 2; sub++) {
                unsigned bits = wsel >> ((quad << 3) + (sub << 2));
                const f32x4& sv = s[j2 * 2 + sub];
                float p0 = (bits & 1u)        ? __builtin_amdgcn_exp2f(sv[0]) : 0.f;
                float p1 = ((bits >> 1) & 1u) ? __builtin_amdgcn_exp2f(sv[1]) : 0.f;
                float p2 = ((bits >> 2) & 1u) ? __builtin_amdgcn_exp2f(sv[2]) : 0.f;
                float p3 = ((bits >> 3) & 1u) ? __builtin_amdgcn_exp2f(sv[3]) : 0.f;
                pk[sub * 2]     = pk2h(p0, p1);
                pk[sub * 2 + 1] = pk2h(p2, p3);
            }
            f16x4 lo = __builtin_shufflevector(pk[0], pk[1], 0, 1, 2, 3);
            f16x4 hi = __builtin_shufflevector(pk[2], pk[3], 0, 1, 2, 3);
            pa[j2] = __builtin_shufflevector(lo, hi, 0, 1, 2, 3, 4, 5, 6, 7);
        }

        // O += P V ; l += P ones   (V fragments from registers)
        __builtin_amdgcn_s_setprio(1);
        #pragma unroll
        for (int j2 = 0; j2 < 2; j2++) {
            ol = mfma16x32(pa[j2], ones, ol);
            #pragma unroll
            for (int jd = 0; jd < 4; jd++) {
                f16x8 bv = __builtin_bit_cast(f16x8, bvr[j2][jd]);
                o[jd] = mfma16x32(pa[j2], bv, o[jd]);
            }
        }
        __builtin_amdgcn_s_setprio(0);
    }

    // epilogue: normalize, stage via this wave's 16 qs rows, coalesced store
    float linv[4];
    #pragma unroll
    for (int rr = 0; rr < 4; rr++) linv[rr] = 1.0f / ol[rr];
    short (*ps)[72] = (short(*)[72])&qs[w << 4];   // wave-private 16 rows
    #pragma unroll
    for (int jd = 0; jd < 4; jd++)
        #pragma unroll
        for (int rr = 0; rr < 4; rr++)
            ps[quad * 4 + rr][jd * 16 + l16] = f2h(o[jd][rr] * linv[rr]);

    #pragma unroll
    for (int k2 = 0; k2 < 2; k2++) {
        int row = (lane >> 3) + k2 * 8;
        int cc = (lane & 7) << 3;
        s16x8 vd = *(const s16x8*)&ps[row][cc];
        *(s16x8*)(xb + ((long)b * NQ + n0 + (w << 4) + row) * DIM + h * 64 + cc) = vd;
    }
}

// ---------------------------------------------------------------------------
extern "C" void kernel_launch(void* const* d_in, const int* in_sizes, int n_in,
                              void* d_out, int out_size, void* d_ws, size_t ws_size,
                              hipStream_t stream)
{
    const float* q     = (const float*)d_in[0];
    const float* kv    = (const float*)d_in[1];
    const float* Wq    = (const float*)d_in[2];
    const float* Wkv   = (const float*)d_in[3];
    const float* Wproj = (const float*)d_in[4];
    const float* bproj = (const float*)d_in[5];
    const int*   mask  = (const int*)d_in[6];
    float* out = (float*)d_out;

    char* ws = (char*)d_ws;
    short* q_h   = (short*)ws; ws += (size_t)4096 * 768 * 2;
    short* kv_h  = (short*)ws; ws += (size_t)8192 * 768 * 2;
    short* Wq_h  = (short*)ws; ws += (size_t)768 * 768 * 2;
    short* Wkv_h = (short*)ws; ws += (size_t)1536 * 768 * 2;
    short* Wp_h  = (short*)ws; ws += (size_t)768 * 768 * 2;
    short* qp    = (short*)ws; ws += (size_t)4096 * 768 * 2;   // [B,H,N,64] fp16
    short* kk    = (short*)ws; ws += (size_t)8192 * 768 * 2;   // [B,H,M,64] fp16
    short* vt    = (short*)ws; ws += (size_t)8192 * 768 * 2;   // [B,H,64,M] fp16
    short* xb    = (short*)ws; ws += (size_t)4096 * 768 * 2;   // [B,N,768]  fp16
    unsigned char* mbytes = (unsigned char*)ws;                // [B,N,M/8] = 1 MB

    prep_kernel<<<9856, 256, 0, stream>>>(q, kv, Wq, Wkv, Wproj, mask,
                                          q_h, kv_h, Wq_h, Wkv_h, Wp_h, mbytes);
    gemm12_kernel<<<960, 256, 0, stream>>>(q_h, Wq_h, kv_h, Wkv_h, qp, kk, vt);
    attn_kernel<<<768, 256, 0, stream>>>(qp, kk, vt, (const unsigned*)mbytes, xb);
    gemm3_kernel<<<768, 256, 0, stream>>>(xb, Wp_h, bproj, out);
}

// Round 11
// 206.587 us; speedup vs baseline: 1.2706x; 1.2706x over previous
//
#include <hip/hip_runtime.h>
#include <hip/hip_bf16.h>

// ---------------------------------------------------------------------------
// Attention_CA: out = Proj( Softmax(mask, scale * (q Wq^T) (kv Wkv^T)_K^T) (kv Wkv^T)_V )
// B=4, N=1024, M=2048, C=768, H=12, d=64.
// R11: restore R7 (best measured of the stable family: 212.7us).
// R10's V-direct-from-L2 was a gather (lane stride 4KB -> 16 cache lines per
// quad) -> attn 113us. Staging exists to coalesce; reverted.
// Session ledger: attn ~50us = dependency-stall plateau (conflicts/barriers/
// TLP/LDS-volume all falsified as limiters, R1-R8); gemm12 ~45-48us = 2ph
// structure ceiling (8-phase/256^2 template needs >=256-block grids, not
// available at these shapes); e2e plateau 211-215us.
// ---------------------------------------------------------------------------

typedef short    s16x8  __attribute__((ext_vector_type(8)));
typedef short    s16x4  __attribute__((ext_vector_type(4)));
typedef float    f32x4  __attribute__((ext_vector_type(4)));
typedef _Float16 f16x8  __attribute__((ext_vector_type(8)));
typedef _Float16 f16x4  __attribute__((ext_vector_type(4)));
typedef _Float16 f16x2  __attribute__((ext_vector_type(2)));

#define NUM_H 12
#define DIM   768
#define NQ    1024
#define MK    2048
#define QK_SCALE_LOG2E 0.18033688f

__device__ __forceinline__ short f2h(float v) {
    _Float16 h = (_Float16)v;                 // RNE
    return __builtin_bit_cast(short, h);
}
__device__ __forceinline__ f32x4 mfma16x32(f16x8 a, f16x8 b, f32x4 c) {
    return __builtin_amdgcn_mfma_f32_16x16x32_f16(a, b, c, 0, 0, 0);
}
__device__ __forceinline__ f16x2 pk2h(float a, float b) {   // RTZ (P only)
    return __builtin_bit_cast(f16x2, __builtin_amdgcn_cvt_pkrtz(a, b));
}

// ------------------- prep: all casts + mask byte-pack ----------------------
__global__ __launch_bounds__(256) void prep_kernel(
    const float* __restrict__ q, const float* __restrict__ kv,
    const float* __restrict__ Wq, const float* __restrict__ Wkv,
    const float* __restrict__ Wp, const int* __restrict__ mask,
    short* __restrict__ q_h, short* __restrict__ kv_h,
    short* __restrict__ Wq_h, short* __restrict__ Wkv_h,
    short* __restrict__ Wp_h, unsigned char* __restrict__ mbytes)
{
    int bid = blockIdx.x;
    if (bid < 5760) {
        const float* s; short* d; long base;
        if (bid < 1536)      { s = q;   d = q_h;   base = (long)bid * 2048; }
        else if (bid < 4608) { s = kv;  d = kv_h;  base = (long)(bid - 1536) * 2048; }
        else if (bid < 4896) { s = Wq;  d = Wq_h;  base = (long)(bid - 4608) * 2048; }
        else if (bid < 5472) { s = Wkv; d = Wkv_h; base = (long)(bid - 4896) * 2048; }
        else                 { s = Wp;  d = Wp_h;  base = (long)(bid - 5472) * 2048; }
        long i = base + threadIdx.x * 8;
        float4 a = *(const float4*)(s + i);
        float4 b = *(const float4*)(s + i + 4);
        s16x8 r;
        r[0] = f2h(a.x); r[1] = f2h(a.y); r[2] = f2h(a.z); r[3] = f2h(a.w);
        r[4] = f2h(b.x); r[5] = f2h(b.y); r[6] = f2h(b.z); r[7] = f2h(b.w);
        *(s16x8*)(d + i) = r;
    } else {
        long base = (long)(bid - 5760) * 2048 + threadIdx.x * 8;
        int4 m0 = *(const int4*)(mask + base);
        int4 m1 = *(const int4*)(mask + base + 4);
        unsigned v = (unsigned)(m0.x != 0)        | ((unsigned)(m0.y != 0) << 1)
                   | ((unsigned)(m0.z != 0) << 2) | ((unsigned)(m0.w != 0) << 3)
                   | ((unsigned)(m1.x != 0) << 4) | ((unsigned)(m1.y != 0) << 5)
                   | ((unsigned)(m1.z != 0) << 6) | ((unsigned)(m1.w != 0) << 7);
        mbytes[base >> 3] = (unsigned char)v;
    }
}

// ---------------------------- GEMM core: C = A @ Bt^T ----------------------
// R7: double-buffered global_load_lds. Each buffer: A[128][64]+B[128][64]
// linear (32KB). Source chunk inverse-XOR-swizzled, fragment reads XOR the
// same key -> conflict-free b128 + wave-linear DMA dest. ONE barrier per
// K-step: stage(next) -> ds_read+MFMA(cur) -> barrier (drain+release).
// mode 0: qp scatter [B,H,N,d] fp16, *QK_SCALE_LOG2E
// mode 1: kv split -> K [B,H,M,d] fp16, V^T [B,H,d,M] fp16
// mode 2: out fp32 = v + bias[col]
__device__ __forceinline__ void gemm_core(
    short* smem,
    const short* __restrict__ A, const short* __restrict__ Bt,
    int Ncols, int mode, const float* __restrict__ bias,
    short* __restrict__ outb, short* __restrict__ outb2,
    float* __restrict__ outf, int bid)
{
    int ntiles = Ncols >> 7;
    int m0 = (bid / ntiles) << 7;
    int n0 = (bid % ntiles) << 7;
    int t = threadIdx.x;
    int w = t >> 6, lane = t & 63, quad = lane >> 4, l16 = lane & 15;
    int wm = (w & 1) << 6, wn = (w >> 1) << 6;

    f32x4 zero4 = {0.f, 0.f, 0.f, 0.f};
    f32x4 acc[4][4];
    for (int i = 0; i < 4; i++)
        for (int j = 0; j < 4; j++) acc[i][j] = zero4;

    // staging geometry (per issue i): LDS bytes [i*4096 + w*1024 + lane*16]
    // row = i*32 + w*8 + lane/8, chunk = lane&7; source chunk = chunk^(row&7)
    int srow = (w << 3) + (lane >> 3);                  // 0..31 (issue-0 row)
    int scol = (((lane & 7) ^ (lane >> 3)) << 3);       // source col in shorts
    const short* Asrc = A + (long)(m0 + srow) * DIM + scol;
    const short* Bsrc = Bt + (long)(n0 + srow) * DIM + scol;
    int dstoff = (w << 9) + (lane << 3);                // shorts; byte w*1024+lane*16

    // buffers: buf0 A@0 B@8192, buf1 A@16384 B@24576 (shorts)
    auto stage = [&](short* bufA, short* bufB, int kt) {
        #pragma unroll
        for (int i = 0; i < 4; i++) {
            __builtin_amdgcn_global_load_lds(
                (const unsigned int*)(Asrc + (long)i * 32 * DIM + kt),
                (unsigned int*)(bufA + dstoff + i * 2048), 16, 0, 0);
            __builtin_amdgcn_global_load_lds(
                (const unsigned int*)(Bsrc + (long)i * 32 * DIM + kt),
                (unsigned int*)(bufB + dstoff + i * 2048), 16, 0, 0);
        }
    };

    int swl = l16 & 7;           // read-side XOR key (row&7 = l16&7)

    stage(smem, smem + 8192, 0);
    __syncthreads();             // prologue drain (unavoidable)

    for (int kt = 0; kt < DIM; kt += 64) {
        short* Ac = smem + ((kt & 64) ? 16384 : 0);
        short* Bc = Ac + 8192;
        if (kt + 64 < DIM) {
            short* An = smem + ((kt & 64) ? 0 : 16384);
            stage(An, An + 8192, kt + 64);      // issue BEFORE compute
        }
        #pragma unroll
        for (int kh = 0; kh < 2; kh++) {
            f16x8 af[4], bfr[4];
            #pragma unroll
            for (int i = 0; i < 4; i++)
                af[i] = __builtin_bit_cast(f16x8, *(const s16x8*)(
                    Ac + ((wm + i * 16 + l16) << 6)
                       + ((((kh << 2) | quad) ^ swl) << 3)));
            #pragma unroll
            for (int j = 0; j < 4; j++)
                bfr[j] = __builtin_bit_cast(f16x8, *(const s16x8*)(
                    Bc + ((wn + j * 16 + l16) << 6)
                       + ((((kh << 2) | quad) ^ swl) << 3)));
            #pragma unroll
            for (int i = 0; i < 4; i++)
                #pragma unroll
                for (int j = 0; j < 4; j++)
                    acc[i][j] = mfma16x32(af[i], bfr[j], acc[i][j]);
        }
        __syncthreads();         // drain prefetch (under MFMA) + release buffer
    }

    if (mode == 2) {
        #pragma unroll
        for (int i = 0; i < 4; i++)
            #pragma unroll
            for (int j = 0; j < 4; j++)
                #pragma unroll
                for (int r = 0; r < 4; r++) {
                    int row = m0 + wm + i * 16 + quad * 4 + r;
                    int col = n0 + wn + j * 16 + l16;
                    outf[(long)row * DIM + col] = acc[i][j][r] + bias[col];
                }
        return;
    }

    short (*Cs)[136] = (short(*)[136])smem;
    bool vreg = (mode == 1) && (n0 >= DIM);

    if (!vreg) {
        float sc = (mode == 0) ? QK_SCALE_LOG2E : 1.0f;
        #pragma unroll
        for (int i = 0; i < 4; i++)
            #pragma unroll
            for (int j = 0; j < 4; j++)
                #pragma unroll
                for (int r = 0; r < 4; r++)
                    Cs[wm + i * 16 + quad * 4 + r][wn + j * 16 + l16] =
                        f2h(acc[i][j][r] * sc);
    } else {
        #pragma unroll
        for (int i = 0; i < 4; i++)
            #pragma unroll
            for (int j = 0; j < 4; j++) {
                int c = wn + j * 16 + l16;
                int r0 = wm + i * 16 + quad * 4;
                s16x4 pk;
                pk[0] = f2h(acc[i][j][0]); pk[1] = f2h(acc[i][j][1]);
                pk[2] = f2h(acc[i][j][2]); pk[3] = f2h(acc[i][j][3]);
                *(s16x4*)&Cs[c][r0] = pk;            // transposed: Cs[dd][m]
            }
    }
    __syncthreads();

    if (!vreg) {
        int hb2 = n0 >> 6;
        long rowsN = (mode == 0) ? NQ : MK;
        int b = (int)(m0 / rowsN);
        int rb = (int)(m0 % rowsN);
        short* ob0 = outb + ((long)(b * NUM_H + hb2) * rowsN + rb) * 64;
        short* ob1 = outb + ((long)(b * NUM_H + hb2 + 1) * rowsN + rb) * 64;
        #pragma unroll
        for (int k2 = 0; k2 < 8; k2++) {
            int ch = k2 * 256 + t;
            int half = ch >> 10, off = ch & 1023;
            s16x8 vd = *(const s16x8*)&Cs[off >> 3][(half << 6) + ((off & 7) << 3)];
            *(s16x8*)((half ? ob1 : ob0) + off * 8) = vd;
        }
    } else {
        int hb2 = (n0 - DIM) >> 6;
        int b = m0 >> 11, rb = m0 & 2047;
        #pragma unroll
        for (int k2 = 0; k2 < 8; k2++) {
            int ch = k2 * 256 + t;
            int c = ch >> 4, woff = (ch & 15) << 3;
            s16x8 vd = *(const s16x8*)&Cs[c][woff];
            int half = c >> 6, dd = c & 63;
            *(s16x8*)(outb2 + (((long)(b * NUM_H + hb2 + half) * 64 + dd) * MK + rb) + woff) = vd;
        }
    }
}

__global__ __launch_bounds__(256) void gemm12_kernel(
    const short* __restrict__ qh, const short* __restrict__ Wqh,
    const short* __restrict__ kvh, const short* __restrict__ Wkvh,
    short* __restrict__ qp, short* __restrict__ kk, short* __restrict__ vt)
{
    __shared__ short smem[32768];      // 64KB: 2 x (A 16KB + B 16KB)
    if (blockIdx.x < 192)
        gemm_core(smem, qh, Wqh, 768, 0, nullptr, qp, nullptr, nullptr, blockIdx.x);
    else
        gemm_core(smem, kvh, Wkvh, 1536, 1, nullptr, kk, vt, nullptr, blockIdx.x - 192);
}

__global__ __launch_bounds__(256) void gemm3_kernel(
    const short* __restrict__ xb, const short* __restrict__ Wph,
    const float* __restrict__ bias, float* __restrict__ out)
{
    __shared__ short smem[32768];
    gemm_core(smem, xb, Wph, 768, 2, bias, nullptr, nullptr, out, blockIdx.x);
}

// ------------------------- flash attention (R1 form, ~51.5us) --------------
// 4 waves x 16 q-rows. K-tile rows PERMUTED at staging so S^T lands in fp16
// K=32 A-fragment order -> PV: 10x mfma_16x16x32, V frags via ds_read_b128.
// ks/vs linear [64][64] + 16B-chunk XOR swizzle (col ^= (row&7)<<3),
// identical on write & read. setprio(1) around MFMA clusters.
__global__ __launch_bounds__(256) void attn_kernel(
    const short* __restrict__ qp, const short* __restrict__ kk,
    const short* __restrict__ vt, const unsigned* __restrict__ mb,
    short* __restrict__ xb)
{
    __shared__ short qs[64][72];       // Q tile; reused as O staging
    __shared__ short ks[64][64];       // K tile, rows permuted, XOR-swizzled
    __shared__ short vs[64][64];       // V^T tile [dd][m], XOR-swizzled

    int bid = blockIdx.x;
    int bh = bid % 48;                 // XCD swizzle: head bh -> XCD bh%8
    int nt = bid / 48;
    int h = bh % NUM_H, b = bh / NUM_H;
    int n0 = nt << 6;
    int t = threadIdx.x, w = t >> 6, lane = t & 63, quad = lane >> 4, l16 = lane & 15;

    const short* qbase = qp + ((long)bh * NQ + n0) * 64;
    const short* kbase = kk + (long)bh * MK * 64;
    const short* vbase = vt + (long)bh * 64 * MK;
    const unsigned* mrow = mb + ((long)b * NQ + n0 + (w << 4) + l16) * 64;

    {   // stage Q tile once
        int qr = t >> 2, c0q = (t & 3) << 4;
        *(s16x8*)&qs[qr][c0q]     = *(const s16x8*)(qbase + qr * 64 + c0q);
        *(s16x8*)&qs[qr][c0q + 8] = *(const s16x8*)(qbase + qr * 64 + c0q + 8);
    }
    __syncthreads();
    f16x8 bq[2];                       // B-frag: this wave's 16 q-rows
    #pragma unroll
    for (int kh = 0; kh < 2; kh++)
        bq[kh] = __builtin_bit_cast(f16x8,
            *(const s16x8*)&qs[(w << 4) + l16][kh * 32 + quad * 8]);

    int sr = t >> 2, c0 = (t & 3) << 4;
    int pr = (sr & 32) + ((sr & 4) << 2) + ((sr & 24) >> 1) + (sr & 3);
    int swk = (pr & 7) << 3;           // XOR key for ks writes (physical row pr)
    int swv = (sr & 7) << 3;           // XOR key for vs writes (physical row sr)
    int swl = (l16 & 7) << 3;          // XOR key for fragment reads (row = *16+l16)
    const short* kp = kbase + (long)sr * 64 + c0;
    const short* vp = vbase + (long)sr * MK + c0;

    s16x8 k0 = *(const s16x8*)(kp);
    s16x8 k1 = *(const s16x8*)(kp + 8);
    s16x8 v0 = *(const s16x8*)(vp);
    s16x8 v1 = *(const s16x8*)(vp + 8);
    uint2 mwv = *(const uint2*)(mrow);

    f32x4 zero4 = {0.f, 0.f, 0.f, 0.f};
    f32x4 o[4], ol = zero4;
    for (int j = 0; j < 4; j++) o[j] = zero4;
    const f16x8 ones = {(_Float16)1.f, (_Float16)1.f, (_Float16)1.f, (_Float16)1.f,
                        (_Float16)1.f, (_Float16)1.f, (_Float16)1.f, (_Float16)1.f};

    for (int mt = 0; mt < MK; mt += 64) {
        __syncthreads();
        *(s16x8*)&ks[pr][c0 ^ swk]       = k0;
        *(s16x8*)&ks[pr][(c0 + 8) ^ swk] = k1;
        *(s16x8*)&vs[sr][c0 ^ swv]       = v0;
        *(s16x8*)&vs[sr][(c0 + 8) ^ swv] = v1;
        unsigned cm0 = mwv.x, cm1 = mwv.y;      // save pre-clobber
        __syncthreads();
        if (mt + 64 < MK) {
            k0 = *(const s16x8*)(kp + (long)(mt + 64) * 64);
            k1 = *(const s16x8*)(kp + (long)(mt + 64) * 64 + 8);
            v0 = *(const s16x8*)(vp + mt + 64);
            v1 = *(const s16x8*)(vp + mt + 64 + 8);
            mwv = *(const uint2*)(mrow + ((mt + 64) >> 5));
        }

        // S^T = K Q^T; s[jj=j2*2+sub][rr] = S[qrow=l16][m=j2*32+quad*8+sub*4+rr]
        f32x4 s[4];
        #pragma unroll
        for (int jj = 0; jj < 4; jj++) s[jj] = zero4;
        __builtin_amdgcn_s_setprio(1);
        #pragma unroll
        for (int kh = 0; kh < 2; kh++)
            #pragma unroll
            for (int jj = 0; jj < 4; jj++) {
                f16x8 ak = __builtin_bit_cast(f16x8,
                    *(const s16x8*)&ks[jj * 16 + l16][(kh * 32 + quad * 8) ^ swl]);
                s[jj] = mfma16x32(ak, bq[kh], s[jj]);
            }
        __builtin_amdgcn_s_setprio(0);

        // p = mask ? exp2(s) : 0, packed to K=32 fp16 A-fragments
        f16x8 pa[2];
        #pragma unroll
        for (int j2 = 0; j2 < 2; j2++) {
            unsigned wsel = j2 ? cm1 : cm0;
            f16x2 pk[4];
            #pragma unroll
            for (int sub = 0; sub < 2; sub++) {
                unsigned bits = wsel >> ((quad << 3) + (sub << 2));
                const f32x4& sv = s[j2 * 2 + sub];
                float p0 = (bits & 1u)        ? __builtin_amdgcn_exp2f(sv[0]) : 0.f;
                float p1 = ((bits >> 1) & 1u) ? __builtin_amdgcn_exp2f(sv[1]) : 0.f;
                float p2 = ((bits >> 2) & 1u) ? __builtin_amdgcn_exp2f(sv[2]) : 0.f;
                float p3 = ((bits >> 3) & 1u) ? __builtin_amdgcn_exp2f(sv[3]) : 0.f;
                pk[sub * 2]     = pk2h(p0, p1);
                pk[sub * 2 + 1] = pk2h(p2, p3);
            }
            f16x4 lo = __builtin_shufflevector(pk[0], pk[1], 0, 1, 2, 3);
            f16x4 hi = __builtin_shufflevector(pk[2], pk[3], 0, 1, 2, 3);
            pa[j2] = __builtin_shufflevector(lo, hi, 0, 1, 2, 3, 4, 5, 6, 7);
        }

        // O += P V ; l += P ones   (K=32: 10 MFMAs, V frags via b128)
        __builtin_amdgcn_s_setprio(1);
        #pragma unroll
        for (int j2 = 0; j2 < 2; j2++) {
            ol = mfma16x32(pa[j2], ones, ol);
            #pragma unroll
            for (int jd = 0; jd < 4; jd++) {
                f16x8 bv = __builtin_bit_cast(f16x8,
                    *(const s16x8*)&vs[jd * 16 + l16][(j2 * 32 + quad * 8) ^ swl]);
                o[jd] = mfma16x32(pa[j2], bv, o[jd]);
            }
        }
        __builtin_amdgcn_s_setprio(0);
    }

    // epilogue: normalize, stage via this wave's 16 qs rows, coalesced store
    float linv[4];
    #pragma unroll
    for (int rr = 0; rr < 4; rr++) linv[rr] = 1.0f / ol[rr];
    short (*ps)[72] = (short(*)[72])&qs[w << 4];   // wave-private 16 rows
    #pragma unroll
    for (int jd = 0; jd < 4; jd++)
        #pragma unroll
        for (int rr = 0; rr < 4; rr++)
            ps[quad * 4 + rr][jd * 16 + l16] = f2h(o[jd][rr] * linv[rr]);

    #pragma unroll
    for (int k2 = 0; k2 < 2; k2++) {
        int row = (lane >> 3) + k2 * 8;
        int cc = (lane & 7) << 3;
        s16x8 vd = *(const s16x8*)&ps[row][cc];
        *(s16x8*)(xb + ((long)b * NQ + n0 + (w << 4) + row) * DIM + h * 64 + cc) = vd;
    }
}

// ---------------------------------------------------------------------------
extern "C" void kernel_launch(void* const* d_in, const int* in_sizes, int n_in,
                              void* d_out, int out_size, void* d_ws, size_t ws_size,
                              hipStream_t stream)
{
    const float* q     = (const float*)d_in[0];
    const float* kv    = (const float*)d_in[1];
    const float* Wq    = (const float*)d_in[2];
    const float* Wkv   = (const float*)d_in[3];
    const float* Wproj = (const float*)d_in[4];
    const float* bproj = (const float*)d_in[5];
    const int*   mask  = (const int*)d_in[6];
    float* out = (float*)d_out;

    char* ws = (char*)d_ws;
    short* q_h   = (short*)ws; ws += (size_t)4096 * 768 * 2;
    short* kv_h  = (short*)ws; ws += (size_t)8192 * 768 * 2;
    short* Wq_h  = (short*)ws; ws += (size_t)768 * 768 * 2;
    short* Wkv_h = (short*)ws; ws += (size_t)1536 * 768 * 2;
    short* Wp_h  = (short*)ws; ws += (size_t)768 * 768 * 2;
    short* qp    = (short*)ws; ws += (size_t)4096 * 768 * 2;   // [B,H,N,64] fp16
    short* kk    = (short*)ws; ws += (size_t)8192 * 768 * 2;   // [B,H,M,64] fp16
    short* vt    = (short*)ws; ws += (size_t)8192 * 768 * 2;   // [B,H,64,M] fp16
    short* xb    = (short*)ws; ws += (size_t)4096 * 768 * 2;   // [B,N,768]  fp16
    unsigned char* mbytes = (unsigned char*)ws;                // [B,N,M/8] = 1 MB

    prep_kernel<<<9856, 256, 0, stream>>>(q, kv, Wq, Wkv, Wproj, mask,
                                          q_h, kv_h, Wq_h, Wkv_h, Wp_h, mbytes);
    gemm12_kernel<<<960, 256, 0, stream>>>(q_h, Wq_h, kv_h, Wkv_h, qp, kk, vt);
    attn_kernel<<<768, 256, 0, stream>>>(qp, kk, vt, (const unsigned*)mbytes, xb);
    gemm3_kernel<<<192, 256, 0, stream>>>(xb, Wp_h, bproj, out);
}